// Round 4
// baseline (184.839 us; speedup 1.0000x reference)
//
#include <hip/hip_runtime.h>
#include <math.h>

#define BINS 10

// Problem constants: BATCH=8388608, NUM_CLASSES=2
constexpr int   NPAIRS = 4194304;       // float4 quads (2 rows x 2 classes each)
constexpr float NTOT_F = 16777216.0f;   // BATCH * NUM_CLASSES

constexpr int G1     = 2048;            // 8 blocks/CU (20 KB LDS each)
constexpr int BLK    = 256;
constexpr int STRIDE = G1 * BLK;        // 524288
constexpr int ITERS  = NPAIRS / STRIDE; // 8 exact -> fully unrolled, no tail
// elements/thread = 4*ITERS = 32  ->  6-bit packed counters can't overflow (<=32 < 64)

// Workspace: blk_pair[b*G1 + block] = {f32 bce-sum(log2), u32 count} -- 160 KB
constexpr size_t WS_PAIR = 0;

__device__ __forceinline__ void proc(float x, bool y1, int tid,
                                     float* __restrict__ lsum,
                                     unsigned long long& cnt64) {
    // z = (y==1) ? -x : x ; t = e^z ; u = 1+t
    // g = |sigmoid(x)-y| = t/u ; bce = max(x,0)-x*y+log1p(e^-|x|) = ln(u) = ln2*log2(u)
    float z = y1 ? -x : x;
    float t = __builtin_amdgcn_exp2f(z * 1.4426950408889634f);
    float u = 1.0f + t;
    float g = t * __builtin_amdgcn_rcpf(u);
    int   b = (int)(g * 9.9999f);        // g in [0,1] -> trunc == floor
    b = b < 9 ? b : 9;                   // clamp (rcp rounding safety)
    float l = __builtin_amdgcn_logf(u);  // log2(u); ln2 applied once at the end
    // ds_add_f32 no-return: fire-and-forget, per-thread column -> no read-latency
    // chain, no bank/same-address conflicts (bank = tid%32), deterministic order.
    atomicAdd(&lsum[b * BLK + tid], l);
    // all 10 counts in one packed u64 register: 6-bit fields, max 32 per field
    cnt64 += 1ull << (6 * b);
}

__global__ __launch_bounds__(BLK) void ghm_main(const float4* __restrict__ x4,
                                                const int2*   __restrict__ t2,
                                                float2*       __restrict__ blk_pair) {
    __shared__ float    lsum[BINS * BLK];   // 10240 B
    __shared__ unsigned lcnt[BINS * BLK];   // 10240 B
    const int tid = threadIdx.x;

#pragma unroll
    for (int b = 0; b < BINS; ++b) lsum[b * BLK + tid] = 0.0f;
    // no barrier: each thread only touches its own columns until the reduce

    unsigned long long cnt64 = 0ull;
    const int base = blockIdx.x * BLK + tid;
#pragma unroll
    for (int k = 0; k < ITERS; ++k) {
        float4 xv = x4[base + k * STRIDE];
        int2   tv = t2[base + k * STRIDE];
        // element (row, c): y = (target[row] == c)
        proc(xv.x, tv.x == 0, tid, lsum, cnt64);
        proc(xv.y, tv.x == 1, tid, lsum, cnt64);
        proc(xv.z, tv.y == 0, tid, lsum, cnt64);
        proc(xv.w, tv.y == 1, tid, lsum, cnt64);
    }

    // unpack packed counters into per-thread LDS columns (plain stores, own column)
#pragma unroll
    for (int b = 0; b < BINS; ++b)
        lcnt[b * BLK + tid] = (unsigned)((cnt64 >> (6 * b)) & 63ull);

    __syncthreads();
    const int wave = tid >> 6;
    const int lane = tid & 63;
    // wave w reduces bins {w, w+4, w+8}: strided reads + 64-lane shuffle tree
    for (int b = wave; b < BINS; b += 4) {
        float    s = lsum[b * BLK + lane]       + lsum[b * BLK + lane + 64]
                   + lsum[b * BLK + lane + 128] + lsum[b * BLK + lane + 192];
        unsigned c = lcnt[b * BLK + lane]       + lcnt[b * BLK + lane + 64]
                   + lcnt[b * BLK + lane + 128] + lcnt[b * BLK + lane + 192];
        for (int off = 32; off > 0; off >>= 1) {
            s += __shfl_down(s, off, 64);
            c += __shfl_down(c, off, 64);
        }
        if (lane == 0) {
            float2 p;
            p.x = s;
            p.y = __uint_as_float(c);
            blk_pair[b * G1 + blockIdx.x] = p;   // one dwordx2, bin-major
        }
    }
}

// Final: 10 waves (one per bin); 32 fully-unrolled independent dwordx2 loads per
// lane -> one memory round-trip; f64 shuffle reduce; thread 0 forms beta (ref
// fp32 arithmetic) and the weighted total. Deterministic.
__global__ __launch_bounds__(640) void ghm_final(const float2* __restrict__ blk_pair,
                                                 float*        __restrict__ out) {
    const int wave = threadIdx.x >> 6;   // 0..9 = bin
    const int lane = threadIdx.x & 63;
    double s = 0.0, c = 0.0;
#pragma unroll
    for (int k = 0; k < G1 / 64; ++k) {
        float2 p = blk_pair[wave * G1 + k * 64 + lane];
        s += (double)p.x;
        c += (double)__float_as_uint(p.y);
    }
    for (int off = 32; off > 0; off >>= 1) {
        s += __shfl_down(s, off, 64);
        c += __shfl_down(c, off, 64);
    }
    __shared__ double Sb[BINS], Cb[BINS];
    if (lane == 0) { Sb[wave] = s; Cb[wave] = c; }
    __syncthreads();
    if (threadIdx.x == 0) {
        float nonempty = 0.0f;
#pragma unroll
        for (int b = 0; b < BINS; ++b) nonempty += (Cb[b] > 0.0) ? 1.0f : 0.0f;
        double tot = 0.0;
#pragma unroll
        for (int b = 0; b < BINS; ++b) {
            float gd   = fmaxf((float)Cb[b] * nonempty, 0.0001f);  // ref fp32 math
            float beta = NTOT_F / gd;
            tot += (double)beta * Sb[b];
        }
        // bce sums kept in log2; apply ln2 once, then mean
        out[0] = (float)(tot * 0.693147180559945309 / (double)NTOT_F);
    }
}

extern "C" void kernel_launch(void* const* d_in, const int* in_sizes, int n_in,
                              void* d_out, int out_size, void* d_ws, size_t ws_size,
                              hipStream_t stream) {
    const float4* x4 = (const float4*)d_in[0];   // [B,2] fp32 -> 2 rows per float4
    const int2*   t2 = (const int2*)d_in[1];     // int32 targets -> 2 rows per int2

    float2* blk_pair = (float2*)((char*)d_ws + WS_PAIR);
    float*  out      = (float*)d_out;

    ghm_main <<<G1, BLK, 0, stream>>>(x4, t2, blk_pair);
    ghm_final<<<1, 640, 0, stream>>>(blk_pair, out);
}

// Round 5
// 120.731 us; speedup vs baseline: 1.5310x; 1.5310x over previous
//
#include <hip/hip_runtime.h>
#include <math.h>

#define BINS 10

// Problem constants: BATCH=8388608, NUM_CLASSES=2
constexpr int   NPAIRS = 4194304;       // float4 quads (2 rows x 2 classes each)
constexpr float NTOT_F = 16777216.0f;   // BATCH * NUM_CLASSES

constexpr int G1     = 2048;
constexpr int BLK    = 256;
constexpr int STRIDE = G1 * BLK;        // 524288
constexpr int ITERS  = NPAIRS / STRIDE; // 8 exact -> fully unrolled, no tail
// elements/thread = 32 -> 6-bit packed count fields can't overflow (<=32 < 64)

// Workspace: blk_pair[b*G1 + block] = {f32 bce-sum(log2), u32 count} -- 160 KB
constexpr size_t WS_PAIR = 0;

struct alignas(8) Pair { float s; unsigned c; };

// Pure-register element processing: no LDS, no atomics in the hot loop.
// R4 lesson: per-element LDS float atomics (ds_add_f32) serialize in the LDS
// pipe (~10x throughput trap); R2/R3's LDS RMW stalls on read latency. With
// only 10 bins, cndmask-select into 10 VGPR accumulators is ~30 VALU ops/el
// and keeps the kernel under the HBM floor.
__device__ __forceinline__ void proc(float x, bool y1,
                                     float* __restrict__ acc,
                                     unsigned long long& cnt64) {
    // z = (y==1) ? -x : x ; t = e^z ; u = 1+t
    // g = |sigmoid(x)-y| = t/u ; bce = max(x,0)-x*y+log1p(e^-|x|) = ln(u) = ln2*log2(u)
    float z = y1 ? -x : x;
    float t = __builtin_amdgcn_exp2f(z * 1.4426950408889634f);
    float u = 1.0f + t;
    float g = t * __builtin_amdgcn_rcpf(u);
    int   b = (int)(g * 9.9999f);        // g in [0,1] -> trunc == floor
    b = b < 9 ? b : 9;                   // clamp (rcp rounding safety)
    float l = __builtin_amdgcn_logf(u);  // log2(u); ln2 applied once at the end
    cnt64 += 1ull << (6 * b);            // all 10 counts packed in one u64
#pragma unroll
    for (int i = 0; i < BINS; ++i)       // v_cmp + v_cndmask + v_add each
        acc[i] += (b == i) ? l : 0.0f;
}

__global__ __launch_bounds__(BLK) void ghm_main(const float4* __restrict__ x4,
                                                const int2*   __restrict__ t2,
                                                Pair*         __restrict__ blk_pair) {
    const int tid  = threadIdx.x;
    const int lane = tid & 63;
    const int wave = tid >> 6;

    float acc[BINS];
#pragma unroll
    for (int b = 0; b < BINS; ++b) acc[b] = 0.0f;
    unsigned long long cnt64 = 0ull;

    const int base = blockIdx.x * BLK + tid;
#pragma unroll
    for (int k = 0; k < ITERS; ++k) {
        float4 xv = x4[base + k * STRIDE];
        int2   tv = t2[base + k * STRIDE];
        // element (row, c): y = (target[row] == c)
        proc(xv.x, tv.x == 0, acc, cnt64);
        proc(xv.y, tv.x == 1, acc, cnt64);
        proc(xv.z, tv.y == 0, acc, cnt64);
        proc(xv.w, tv.y == 1, acc, cnt64);
    }

    // unpack counts, then 64-lane shuffle-tree reduce per bin (once per kernel)
    unsigned cnt[BINS];
#pragma unroll
    for (int b = 0; b < BINS; ++b) cnt[b] = (unsigned)((cnt64 >> (6 * b)) & 63ull);
#pragma unroll
    for (int b = 0; b < BINS; ++b) {
        for (int off = 32; off > 0; off >>= 1) {
            acc[b] += __shfl_down(acc[b], off, 64);
            cnt[b] += __shfl_down(cnt[b], off, 64);
        }
    }

    // tiny cross-wave reduce: 4 waves x 10 pairs in LDS (320 B)
    __shared__ Pair red[4][BINS];
    if (lane == 0) {
#pragma unroll
        for (int b = 0; b < BINS; ++b) red[wave][b] = Pair{acc[b], cnt[b]};
    }
    __syncthreads();
    if (tid < BINS) {
        float    s = red[0][tid].s + red[1][tid].s + red[2][tid].s + red[3][tid].s;
        unsigned c = red[0][tid].c + red[1][tid].c + red[2][tid].c + red[3][tid].c;
        blk_pair[tid * G1 + blockIdx.x] = Pair{s, c};   // bin-major for final kernel
    }
}

// Final: 10 waves (one per bin); 32 fully-unrolled independent dwordx2 loads per
// lane -> one memory round-trip; f64 shuffle reduce; thread 0 forms beta (ref
// fp32 arithmetic) and the weighted total. Deterministic.
__global__ __launch_bounds__(640) void ghm_final(const Pair* __restrict__ blk_pair,
                                                 float*      __restrict__ out) {
    const int wave = threadIdx.x >> 6;   // 0..9 = bin
    const int lane = threadIdx.x & 63;
    double s = 0.0, c = 0.0;
#pragma unroll
    for (int k = 0; k < G1 / 64; ++k) {
        Pair p = blk_pair[wave * G1 + k * 64 + lane];
        s += (double)p.s;
        c += (double)p.c;
    }
    for (int off = 32; off > 0; off >>= 1) {
        s += __shfl_down(s, off, 64);
        c += __shfl_down(c, off, 64);
    }
    __shared__ double Sb[BINS], Cb[BINS];
    if (lane == 0) { Sb[wave] = s; Cb[wave] = c; }
    __syncthreads();
    if (threadIdx.x == 0) {
        float nonempty = 0.0f;
#pragma unroll
        for (int b = 0; b < BINS; ++b) nonempty += (Cb[b] > 0.0) ? 1.0f : 0.0f;
        double tot = 0.0;
#pragma unroll
        for (int b = 0; b < BINS; ++b) {
            float gd   = fmaxf((float)Cb[b] * nonempty, 0.0001f);  // ref fp32 math
            float beta = NTOT_F / gd;
            tot += (double)beta * Sb[b];
        }
        // bce sums kept in log2; apply ln2 once, then mean
        out[0] = (float)(tot * 0.693147180559945309 / (double)NTOT_F);
    }
}

extern "C" void kernel_launch(void* const* d_in, const int* in_sizes, int n_in,
                              void* d_out, int out_size, void* d_ws, size_t ws_size,
                              hipStream_t stream) {
    const float4* x4 = (const float4*)d_in[0];   // [B,2] fp32 -> 2 rows per float4
    const int2*   t2 = (const int2*)d_in[1];     // int32 targets -> 2 rows per int2

    Pair*  blk_pair = (Pair*)((char*)d_ws + WS_PAIR);
    float* out      = (float*)d_out;

    ghm_main <<<G1, BLK, 0, stream>>>(x4, t2, blk_pair);
    ghm_final<<<1, 640, 0, stream>>>(blk_pair, out);
}